// Round 9
// baseline (37.067 us; speedup 1.0000x reference)
//
#include <hip/hip_runtime.h>

#define B_SZ     2
#define E_EDGES  16384
#define N_NODES  4096
#define NTOT     (B_SZ * N_NODES)   // 8192 nodes
#define NV       (B_SZ * E_EDGES)   // 32768 edges / queries
#define DVTOT    128
#define LOG2_E   14
#define CAP      32                 // bucket capacity (Poisson(4): P(>=32) ~ 1e-19)

// padded LDS index: insert 4-float gap every 16 floats -> head h starts at h*20
// -> the 8 heads' ds_read_b128 broadcasts land on disjoint bank quads
__device__ __forceinline__ int padidx(int f) { return f + ((f >> 4) << 2); }

__global__ __launch_bounds__(256) void zero_counts(int4* __restrict__ p) {
    int i = blockIdx.x * blockDim.x + threadIdx.x;   // 4096 int4 = 64 KB
    p[i] = make_int4(0, 0, 0, 0);
}

// One pass over all 32768 edges/queries: bucket edges by col-node, queries by q-node.
__global__ __launch_bounds__(256) void fill_all(
    const int* __restrict__ qidx,
    const int* __restrict__ vidx,
    int*  __restrict__ ecnt,   // NTOT
    int*  __restrict__ qcnt,   // NTOT
    int2* __restrict__ ebuf,   // NTOT*CAP  {e, global key row}
    int*  __restrict__ qbuf)   // NTOT*CAP  e | (suppress<<31)
{
    int e = blockIdx.x * blockDim.x + threadIdx.x;
    if (e >= NV) return;
    int ofs = (e >> LOG2_E) * N_NODES;

    int2 vi = ((const int2*)vidx)[e];
    int row = vi.x + ofs;
    int col = vi.y + ofs;
    int p = atomicAdd(&ecnt[col], 1);
    if (p < CAP) ebuf[col * CAP + p] = make_int2(e, row);

    int2 qi = ((const int2*)qidx)[e];
    int g  = qi.y + ofs;
    int pq = atomicAdd(&qcnt[g], 1);
    if (pq < CAP) qbuf[g * CAP + pq] = e | ((qi.x == qi.y) ? 0x80000000 : 0);
}

#define KACC(SLOT, C, V)                                                  \
    { const float4* kp = (const float4*)&sk[wid][SLOT][C][h20];           \
      float4 k0=kp[0],k1=kp[1],k2=kp[2],k3=kp[3];                         \
      float kk[16]={k0.x,k0.y,k0.z,k0.w,k1.x,k1.y,k1.z,k1.w,              \
                    k2.x,k2.y,k2.z,k2.w,k3.x,k3.y,k3.z,k3.w};             \
      _Pragma("unroll") for (int i=0;i<16;++i){                           \
          ks[i]+=kk[i]; kva[i]+=kk[i]*(V).x; kvb[i]+=kk[i]*(V).y; } }

#define QOUT(SLOT, C, T)                                                  \
    { const float4* qp = (const float4*)&sq[wid][SLOT][C][h20];           \
      float4 q0=qp[0],q1=qp[1],q2=qp[2],q3=qp[3];                         \
      float qq[16]={q0.x,q0.y,q0.z,q0.w,q1.x,q1.y,q1.z,q1.w,              \
                    q2.x,q2.y,q2.z,q2.w,q3.x,q3.y,q3.z,q3.w};             \
      float sa=0.f,sb=0.f,w=0.f;                                          \
      _Pragma("unroll") for (int i=0;i<16;++i){                           \
          sa+=qq[i]*kva[i]; sb+=qq[i]*kvb[i]; w+=qq[i]*ks[i]; }           \
      float den=(w==0.f)?1e-5f:w; float inv=1.f/den;                      \
      float2 o; o.x=((T)<0)?0.f:sa*inv; o.y=((T)<0)?0.f:sb*inv;           \
      *(float2*)(out + (size_t)((T)&0x7FFFFFFF)*DVTOT + f2) = o; }

// TWO nodes per WAVE (8 per 256-thread block). Both nodes' scalar+vector
// prologues issue before either compute; node B's fetch hides under A's math.
// lane l: head h = l>>3, columns j = 2*(l&7), +1.
__global__ __launch_bounds__(256, 4) void attn_node(
    const float* __restrict__ qv,
    const float* __restrict__ keys,
    const float* __restrict__ vals,
    const int*   __restrict__ ecnt,
    const int*   __restrict__ qcnt,
    const int2*  __restrict__ ebuf,
    const int*   __restrict__ qbuf,
    float*       __restrict__ out)
{
    __shared__ float sk[4][2][4][160];   // [wave][node][chunk][padded row]
    __shared__ float sq[4][2][4][160];

    int wid  = threadIdx.x >> 6;
    int lane = threadIdx.x & 63;
    int gA = __builtin_amdgcn_readfirstlane(blockIdx.x * 8 + wid * 2);
    int gB = gA + 1;

    int h20 = (lane >> 3) * 20;
    int f2  = 2 * lane;
    int pf2 = padidx(f2);

    const int2* ebA = ebuf + (size_t)gA * CAP;
    const int*  qbA = qbuf + (size_t)gA * CAP;
    const int2* ebB = ebuf + (size_t)gB * CAP;
    const int*  qbB = qbuf + (size_t)gB * CAP;

    // scalar prologue: counts + speculative first-4 records, all independent
    int qcA = qcnt[gA], qcB = qcnt[gB];
    int ecA = ecnt[gA], ecB = ecnt[gB];
    int qtA[4], qtB[4]; int2 erA[4], erB[4];
#pragma unroll
    for (int c = 0; c < 4; ++c) {
        qtA[c] = qbA[c]; qtB[c] = qbB[c];
        erA[c] = ebA[c]; erB[c] = ebB[c];
    }

    int nqA = qcA < CAP ? qcA : CAP;
    int nqB = qcB < CAP ? qcB : CAP;
    if ((nqA | nqB) == 0) return;              // wave-uniform
    int dgA = nqA ? (ecA < CAP ? ecA : CAP) : 0;
    int dgB = nqB ? (ecB < CAP ? ecB : CAP) : 0;
    int dgA0 = dgA < 4 ? dgA : 4, dgB0 = dgB < 4 ? dgB : 4;
    int nqA0 = nqA < 4 ? nqA : 4, nqB0 = nqB < 4 ? nqB : 4;

    // chunk-0 vector loads for BOTH nodes, issued together
    float2 vA[4], vB[4];
#pragma unroll
    for (int c = 0; c < 4; ++c)
        if (c < dgA0) {
            *(float2*)&sk[wid][0][c][pf2] =
                *(const float2*)(keys + (size_t)erA[c].y * DVTOT + f2);
            vA[c] = *(const float2*)(vals + (size_t)erA[c].x * DVTOT + f2);
        }
#pragma unroll
    for (int c = 0; c < 4; ++c)
        if (c < nqA0)
            *(float2*)&sq[wid][0][c][pf2] =
                *(const float2*)(qv + (size_t)(qtA[c] & 0x7FFFFFFF) * DVTOT + f2);
#pragma unroll
    for (int c = 0; c < 4; ++c)
        if (c < dgB0) {
            *(float2*)&sk[wid][1][c][pf2] =
                *(const float2*)(keys + (size_t)erB[c].y * DVTOT + f2);
            vB[c] = *(const float2*)(vals + (size_t)erB[c].x * DVTOT + f2);
        }
#pragma unroll
    for (int c = 0; c < 4; ++c)
        if (c < nqB0)
            *(float2*)&sq[wid][1][c][pf2] =
                *(const float2*)(qv + (size_t)(qtB[c] & 0x7FFFFFFF) * DVTOT + f2);
    __builtin_amdgcn_wave_barrier();

    float kva[16], kvb[16], ks[16];

    // ---------------- node A ----------------
    if (nqA) {
#pragma unroll
        for (int i = 0; i < 16; ++i) { kva[i]=0.f; kvb[i]=0.f; ks[i]=0.f; }
#pragma unroll
        for (int c = 0; c < 4; ++c) if (c < dgA0) KACC(0, c, vA[c]);
        if (dgA > 4) {
            for (int base = 4; base < dgA; base += 4) {
                int n = dgA - base; if (n > 4) n = 4;
                int2 r[4]; float2 vv[4];
#pragma unroll
                for (int c = 0; c < 4; ++c) if (c < n) r[c] = ebA[base + c];
#pragma unroll
                for (int c = 0; c < 4; ++c)
                    if (c < n) vv[c] = *(const float2*)(vals + (size_t)r[c].x * DVTOT + f2);
                __builtin_amdgcn_wave_barrier();
#pragma unroll
                for (int c = 0; c < 4; ++c)
                    if (c < n) *(float2*)&sk[wid][0][c][pf2] =
                        *(const float2*)(keys + (size_t)r[c].y * DVTOT + f2);
                __builtin_amdgcn_wave_barrier();
#pragma unroll
                for (int c = 0; c < 4; ++c) if (c < n) KACC(0, c, vv[c]);
            }
        }
#pragma unroll
        for (int c = 0; c < 4; ++c) if (c < nqA0) QOUT(0, c, qtA[c]);
        if (nqA > 4) {
            for (int base = 4; base < nqA; base += 4) {
                int n = nqA - base; if (n > 4) n = 4;
                int t[4];
#pragma unroll
                for (int c = 0; c < 4; ++c) if (c < n) t[c] = qbA[base + c];
                __builtin_amdgcn_wave_barrier();
#pragma unroll
                for (int c = 0; c < 4; ++c)
                    if (c < n) *(float2*)&sq[wid][0][c][pf2] =
                        *(const float2*)(qv + (size_t)(t[c] & 0x7FFFFFFF) * DVTOT + f2);
                __builtin_amdgcn_wave_barrier();
#pragma unroll
                for (int c = 0; c < 4; ++c) if (c < n) QOUT(0, c, t[c]);
            }
        }
    }

    // ---------------- node B ----------------
    if (nqB) {
#pragma unroll
        for (int i = 0; i < 16; ++i) { kva[i]=0.f; kvb[i]=0.f; ks[i]=0.f; }
#pragma unroll
        for (int c = 0; c < 4; ++c) if (c < dgB0) KACC(1, c, vB[c]);
        if (dgB > 4) {
            for (int base = 4; base < dgB; base += 4) {
                int n = dgB - base; if (n > 4) n = 4;
                int2 r[4]; float2 vv[4];
#pragma unroll
                for (int c = 0; c < 4; ++c) if (c < n) r[c] = ebB[base + c];
#pragma unroll
                for (int c = 0; c < 4; ++c)
                    if (c < n) vv[c] = *(const float2*)(vals + (size_t)r[c].x * DVTOT + f2);
                __builtin_amdgcn_wave_barrier();
#pragma unroll
                for (int c = 0; c < 4; ++c)
                    if (c < n) *(float2*)&sk[wid][1][c][pf2] =
                        *(const float2*)(keys + (size_t)r[c].y * DVTOT + f2);
                __builtin_amdgcn_wave_barrier();
#pragma unroll
                for (int c = 0; c < 4; ++c) if (c < n) KACC(1, c, vv[c]);
            }
        }
#pragma unroll
        for (int c = 0; c < 4; ++c) if (c < nqB0) QOUT(1, c, qtB[c]);
        if (nqB > 4) {
            for (int base = 4; base < nqB; base += 4) {
                int n = nqB - base; if (n > 4) n = 4;
                int t[4];
#pragma unroll
                for (int c = 0; c < 4; ++c) if (c < n) t[c] = qbB[base + c];
                __builtin_amdgcn_wave_barrier();
#pragma unroll
                for (int c = 0; c < 4; ++c)
                    if (c < n) *(float2*)&sq[wid][1][c][pf2] =
                        *(const float2*)(qv + (size_t)(t[c] & 0x7FFFFFFF) * DVTOT + f2);
                __builtin_amdgcn_wave_barrier();
#pragma unroll
                for (int c = 0; c < 4; ++c) if (c < n) QOUT(1, c, t[c]);
            }
        }
    }
}

extern "C" void kernel_launch(void* const* d_in, const int* in_sizes, int n_in,
                              void* d_out, int out_size, void* d_ws, size_t ws_size,
                              hipStream_t stream) {
    const float* qv   = (const float*)d_in[0];
    const float* keys = (const float*)d_in[1];
    const float* vals = (const float*)d_in[2];
    const int*   qidx = (const int*)d_in[3];
    const int*   vidx = (const int*)d_in[4];
    float* out = (float*)d_out;

    char* ws = (char*)d_ws;
    int*  ecnt = (int*)ws;                                // NTOT
    int*  qcnt = ecnt + NTOT;                             // NTOT
    int2* ebuf = (int2*)(qcnt + NTOT);                    // NTOT*CAP int2
    int*  qbuf = (int*)(ebuf + (size_t)NTOT * CAP);       // NTOT*CAP int

    zero_counts<<<16, 256, 0, stream>>>((int4*)ws);       // 64 KB (counts only)
    fill_all<<<(NV + 255) / 256, 256, 0, stream>>>(qidx, vidx, ecnt, qcnt, ebuf, qbuf);
    attn_node<<<NTOT / 8, 256, 0, stream>>>(qv, keys, vals, ecnt, qcnt, ebuf, qbuf, out);
}

// Round 10
// 34.996 us; speedup vs baseline: 1.0592x; 1.0592x over previous
//
#include <hip/hip_runtime.h>

#define B_SZ     2
#define E_EDGES  16384
#define N_NODES  4096
#define NTOT     (B_SZ * N_NODES)   // 8192 nodes
#define NV       (B_SZ * E_EDGES)   // 32768 edges / queries
#define DVTOT    128
#define LOG2_E   14
#define CAP      32                 // bucket capacity (Poisson(4): P(>=32) ~ 1e-19)

// padded LDS index: insert 4-float gap every 16 floats -> head h starts at h*20
// -> the 8 heads' ds_read_b128 broadcasts land on disjoint bank quads
__device__ __forceinline__ int padidx(int f) { return f + ((f >> 4) << 2); }

__global__ __launch_bounds__(256) void zero_counts(int4* __restrict__ p) {
    int i = blockIdx.x * blockDim.x + threadIdx.x;   // 4096 int4 = 64 KB
    p[i] = make_int4(0, 0, 0, 0);
}

// 65536 threads: t < NV -> edge-side bucket insert; t >= NV -> query-side.
// One {load -> atomic -> store} chain per thread.
__global__ __launch_bounds__(256) void fill_split(
    const int* __restrict__ qidx,
    const int* __restrict__ vidx,
    int*  __restrict__ ecnt,   // NTOT
    int*  __restrict__ qcnt,   // NTOT
    int2* __restrict__ ebuf,   // NTOT*CAP  {e, global key row}
    int*  __restrict__ qbuf)   // NTOT*CAP  e | (suppress<<31)
{
    int t = blockIdx.x * blockDim.x + threadIdx.x;
    if (t < NV) {
        int e = t;
        int ofs = (e >> LOG2_E) * N_NODES;
        int2 vi = ((const int2*)vidx)[e];
        int row = vi.x + ofs;
        int col = vi.y + ofs;
        int p = atomicAdd(&ecnt[col], 1);
        if (p < CAP) ebuf[col * CAP + p] = make_int2(e, row);
    } else {
        int e = t - NV;
        int ofs = (e >> LOG2_E) * N_NODES;
        int2 qi = ((const int2*)qidx)[e];
        int g  = qi.y + ofs;
        int pq = atomicAdd(&qcnt[g], 1);
        if (pq < CAP) qbuf[g * CAP + pq] = e | ((qi.x == qi.y) ? 0x80000000 : 0);
    }
}

#define KACC(C)                                                          \
    {                                                                    \
        const float4* kp = (const float4*)&sk[wid][C][h20];              \
        float4 k0 = kp[0], k1 = kp[1], k2 = kp[2], k3 = kp[3];           \
        float kk[16] = {k0.x,k0.y,k0.z,k0.w, k1.x,k1.y,k1.z,k1.w,        \
                        k2.x,k2.y,k2.z,k2.w, k3.x,k3.y,k3.z,k3.w};       \
        _Pragma("unroll")                                                \
        for (int i = 0; i < 16; ++i) {                                   \
            ks[i]  += kk[i];                                             \
            kva[i] += kk[i] * vvv[C].x;                                  \
            kvb[i] += kk[i] * vvv[C].y;                                  \
        }                                                                \
    }

#define QOUT(C, TREG)                                                    \
    {                                                                    \
        const float4* qp = (const float4*)&sq[wid][C][h20];              \
        float4 q0 = qp[0], q1 = qp[1], q2 = qp[2], q3 = qp[3];           \
        float qq[16] = {q0.x,q0.y,q0.z,q0.w, q1.x,q1.y,q1.z,q1.w,        \
                        q2.x,q2.y,q2.z,q2.w, q3.x,q3.y,q3.z,q3.w};       \
        float sa = 0.0f, sb = 0.0f, w = 0.0f;                            \
        _Pragma("unroll")                                                \
        for (int i = 0; i < 16; ++i) {                                   \
            sa += qq[i] * kva[i];                                        \
            sb += qq[i] * kvb[i];                                        \
            w  += qq[i] * ks[i];                                         \
        }                                                                \
        float den = (w == 0.0f) ? 1e-5f : w;                             \
        float inv = 1.0f / den;                                          \
        float2 o;                                                        \
        o.x = ((TREG) < 0) ? 0.0f : sa * inv;                            \
        o.y = ((TREG) < 0) ? 0.0f : sb * inv;                            \
        *(float2*)(out + (size_t)((TREG) & 0x7FFFFFFF) * DVTOT + f2) = o; \
    }

// One node per WAVE (4 nodes / 256-thread block), no block barriers.
// lane l: head h = l>>3, columns j = 2*(l&7), +1.
// Prologue: counts + speculative first-4 records of BOTH buckets issued
// together (all independent s_loads); counts only gate use.
__global__ __launch_bounds__(256, 6) void attn_node(
    const float* __restrict__ qv,
    const float* __restrict__ keys,
    const float* __restrict__ vals,
    const int*   __restrict__ ecnt,
    const int*   __restrict__ qcnt,
    const int2*  __restrict__ ebuf,
    const int*   __restrict__ qbuf,
    float*       __restrict__ out)
{
    __shared__ float sk[4][4][160];   // [wave][chunk][padded row]
    __shared__ float sq[4][4][160];

    int wid  = threadIdx.x >> 6;
    int lane = threadIdx.x & 63;
    int g    = __builtin_amdgcn_readfirstlane(blockIdx.x * 4 + wid);

    int h20 = (lane >> 3) * 20;
    int f2  = 2 * lane;
    int pf2 = padidx(f2);

    const int2* eb = ebuf + (size_t)g * CAP;
    const int*  qb = qbuf + (size_t)g * CAP;

    // parallel scalar prologue: counts + speculative records, all independent
    int nq = qcnt[g];
    int dg = ecnt[g];
    int qt[4]; int2 er[4];
#pragma unroll
    for (int c = 0; c < 4; ++c) { qt[c] = qb[c]; er[c] = eb[c]; }

    if (nq > CAP) nq = CAP;
    if (dg > CAP) dg = CAP;
    if (nq == 0) return;                         // wave-uniform
    int nq0 = nq < 4 ? nq : 4;
    int dg0 = dg < 4 ? dg : 4;

    // chunk-0 vector loads for BOTH phases, issued together
    float2 vvv[4];
#pragma unroll
    for (int c = 0; c < 4; ++c)
        if (c < dg0) {
            *(float2*)&sk[wid][c][pf2] =
                *(const float2*)(keys + (size_t)er[c].y * DVTOT + f2);
            vvv[c] = *(const float2*)(vals + (size_t)er[c].x * DVTOT + f2);
        }
#pragma unroll
    for (int c = 0; c < 4; ++c)
        if (c < nq0)
            *(float2*)&sq[wid][c][pf2] =
                *(const float2*)(qv + (size_t)(qt[c] & 0x7FFFFFFF) * DVTOT + f2);
    __builtin_amdgcn_wave_barrier();

    float kva[16], kvb[16], ks[16];
#pragma unroll
    for (int i = 0; i < 16; ++i) { kva[i] = 0.0f; kvb[i] = 0.0f; ks[i] = 0.0f; }

    // chunk-0 k accumulate
#pragma unroll
    for (int c = 0; c < 4; ++c)
        if (c < dg0) KACC(c);

    // k remainder (deg > 4), exactly count-bounded
    for (int base = 4; base < dg; base += 4) {
        int n = dg - base; if (n > 4) n = 4;
        int2 r[4];
#pragma unroll
        for (int c = 0; c < 4; ++c) if (c < n) r[c] = eb[base + c];
#pragma unroll
        for (int c = 0; c < 4; ++c)
            if (c < n) vvv[c] = *(const float2*)(vals + (size_t)r[c].x * DVTOT + f2);
        __builtin_amdgcn_wave_barrier();         // prior sk reads done (WAR)
#pragma unroll
        for (int c = 0; c < 4; ++c)
            if (c < n) *(float2*)&sk[wid][c][pf2] =
                *(const float2*)(keys + (size_t)r[c].y * DVTOT + f2);
        __builtin_amdgcn_wave_barrier();
#pragma unroll
        for (int c = 0; c < 4; ++c) if (c < n) KACC(c);
    }

    // q outputs, chunk 0 (rows already staged)
#pragma unroll
    for (int c = 0; c < 4; ++c)
        if (c < nq0) QOUT(c, qt[c]);

    // q remainder (nq > 4), exactly count-bounded
    for (int base = 4; base < nq; base += 4) {
        int n = nq - base; if (n > 4) n = 4;
        int t[4];
#pragma unroll
        for (int c = 0; c < 4; ++c) if (c < n) t[c] = qb[base + c];
        float2 qv2[4];
#pragma unroll
        for (int c = 0; c < 4; ++c)
            if (c < n) qv2[c] = *(const float2*)(qv + (size_t)(t[c] & 0x7FFFFFFF) * DVTOT + f2);
        __builtin_amdgcn_wave_barrier();         // prior sq reads done (WAR)
#pragma unroll
        for (int c = 0; c < 4; ++c)
            if (c < n) *(float2*)&sq[wid][c][pf2] = qv2[c];
        __builtin_amdgcn_wave_barrier();
#pragma unroll
        for (int c = 0; c < 4; ++c) if (c < n) QOUT(c, t[c]);
    }
}

extern "C" void kernel_launch(void* const* d_in, const int* in_sizes, int n_in,
                              void* d_out, int out_size, void* d_ws, size_t ws_size,
                              hipStream_t stream) {
    const float* qv   = (const float*)d_in[0];
    const float* keys = (const float*)d_in[1];
    const float* vals = (const float*)d_in[2];
    const int*   qidx = (const int*)d_in[3];
    const int*   vidx = (const int*)d_in[4];
    float* out = (float*)d_out;

    char* ws = (char*)d_ws;
    int*  ecnt = (int*)ws;                                // NTOT
    int*  qcnt = ecnt + NTOT;                             // NTOT
    int2* ebuf = (int2*)(qcnt + NTOT);                    // NTOT*CAP int2
    int*  qbuf = (int*)(ebuf + (size_t)NTOT * CAP);       // NTOT*CAP int

    zero_counts<<<16, 256, 0, stream>>>((int4*)ws);       // 64 KB (counts only)
    fill_split<<<(2 * NV) / 256, 256, 0, stream>>>(qidx, vidx, ecnt, qcnt, ebuf, qbuf);
    attn_node<<<NTOT / 4, 256, 0, stream>>>(qv, keys, vals, ecnt, qcnt, ebuf, qbuf, out);
}

// Round 11
// 30.910 us; speedup vs baseline: 1.1992x; 1.1322x over previous
//
#include <hip/hip_runtime.h>

#define B_SZ     2
#define E_EDGES  16384
#define N_NODES  4096
#define NTOT     (B_SZ * N_NODES)   // 8192 nodes
#define NV       (B_SZ * E_EDGES)   // 32768 edges / queries
#define DVTOT    128
#define LOG2_E   14
#define CAP      32                 // bucket capacity (Poisson(4): P(>=32) ~ 1e-19)

// ws zero region: ecnt[NTOT] qcnt[NTOT] ebuf[NTOT*CAP] int2, qbuf[NTOT*CAP] int
// = 64KB + 2MB + 1MB = 3,211,264 B = 200704 int4
#define ZERO_INT4 200704

// padded LDS index: insert 4-float gap every 16 floats -> head h starts at h*20
__device__ __forceinline__ int padidx(int f) { return f + ((f >> 4) << 2); }

__global__ __launch_bounds__(256) void zero_ws(int4* __restrict__ p) {
    int i = blockIdx.x * blockDim.x + threadIdx.x;
    p[i] = make_int4(0, 0, 0, 0);
}

// 65536 threads: t < NV -> edge-side bucket insert; t >= NV -> query-side.
// One {load -> atomic -> store} chain per thread. Sentinel coding (e+1).
__global__ __launch_bounds__(256) void fill_split(
    const int* __restrict__ qidx,
    const int* __restrict__ vidx,
    int*  __restrict__ ecnt,   // NTOT (cursors only)
    int*  __restrict__ qcnt,   // NTOT (cursors only)
    int2* __restrict__ ebuf,   // NTOT*CAP  {e+1, global key row}
    int*  __restrict__ qbuf)   // NTOT*CAP  (e+1) | (suppress<<31)
{
    int t = blockIdx.x * blockDim.x + threadIdx.x;
    if (t < NV) {
        int e = t;
        int ofs = (e >> LOG2_E) * N_NODES;
        int2 vi = ((const int2*)vidx)[e];
        int col = vi.y + ofs;
        int p = atomicAdd(&ecnt[col], 1);
        if (p < CAP) ebuf[col * CAP + p] = make_int2(e + 1, vi.x + ofs);
    } else {
        int e = t - NV;
        int ofs = (e >> LOG2_E) * N_NODES;
        int2 qi = ((const int2*)qidx)[e];
        int g  = qi.y + ofs;
        int pq = atomicAdd(&qcnt[g], 1);
        if (pq < CAP) qbuf[g * CAP + pq] = (e + 1) | ((qi.x == qi.y) ? 0x80000000 : 0);
    }
}

#define KACC(C, V)                                                       \
    {                                                                    \
        const float4* kp = (const float4*)&sk[wid][C][h20];              \
        float4 k0 = kp[0], k1 = kp[1], k2 = kp[2], k3 = kp[3];           \
        float kk[16] = {k0.x,k0.y,k0.z,k0.w, k1.x,k1.y,k1.z,k1.w,        \
                        k2.x,k2.y,k2.z,k2.w, k3.x,k3.y,k3.z,k3.w};       \
        _Pragma("unroll")                                                \
        for (int i = 0; i < 16; ++i) {                                   \
            ks[i]  += kk[i];                                             \
            kva[i] += kk[i] * (V).x;                                     \
            kvb[i] += kk[i] * (V).y;                                     \
        }                                                                \
    }

#define QOUT(C, TREG)                                                    \
    {                                                                    \
        const float4* qp = (const float4*)&sq[wid][C][h20];              \
        float4 q0 = qp[0], q1 = qp[1], q2 = qp[2], q3 = qp[3];           \
        float qq[16] = {q0.x,q0.y,q0.z,q0.w, q1.x,q1.y,q1.z,q1.w,        \
                        q2.x,q2.y,q2.z,q2.w, q3.x,q3.y,q3.z,q3.w};       \
        float sa = 0.0f, sb = 0.0f, w = 0.0f;                            \
        _Pragma("unroll")                                                \
        for (int i = 0; i < 16; ++i) {                                   \
            sa += qq[i] * kva[i];                                        \
            sb += qq[i] * kvb[i];                                        \
            w  += qq[i] * ks[i];                                         \
        }                                                                \
        float den = (w == 0.0f) ? 1e-5f : w;                             \
        float inv = 1.0f / den;                                          \
        float2 o;                                                        \
        o.x = ((TREG) < 0) ? 0.0f : sa * inv;                            \
        o.y = ((TREG) < 0) ? 0.0f : sb * inv;                            \
        *(float2*)(out + (size_t)(((TREG) & 0x7FFFFFFF) - 1) * DVTOT + f2) = o; \
    }

// One node per WAVE (4 per 256-thread block), no block barriers.
// lane l: head h = l>>3, columns j = 2*(l&7), +1.
// Prologue: records 0..7 of BOTH buckets scalar-loaded in parallel; chunk-0
// vector loads issued unconditionally (clamped records), straight-line.
__global__ __launch_bounds__(256) void attn_node(
    const float* __restrict__ qv,
    const float* __restrict__ keys,
    const float* __restrict__ vals,
    const int2*  __restrict__ ebuf,
    const int*   __restrict__ qbuf,
    float*       __restrict__ out)
{
    __shared__ float sk[4][4][160];   // [wave][chunk][padded row]
    __shared__ float sq[4][4][160];

    int wid  = threadIdx.x >> 6;
    int lane = threadIdx.x & 63;
    int g    = __builtin_amdgcn_readfirstlane(blockIdx.x * 4 + wid);

    int h20 = (lane >> 3) * 20;
    int f2  = 2 * lane;
    int pf2 = padidx(f2);

    const int2* eb = ebuf + (size_t)g * CAP;
    const int*  qb = qbuf + (size_t)g * CAP;

    // parallel scalar prologue: first 8 records of both buckets (SGPRs)
    int qt[8]; int2 er[8];
#pragma unroll
    for (int c = 0; c < 8; ++c) { qt[c] = qb[c]; er[c] = eb[c]; }

    int nq0 = qt[0] ? (qt[1] ? (qt[2] ? (qt[3] ? 4 : 3) : 2) : 1) : 0;
    if (nq0 == 0) return;                            // wave-uniform
    int dg0 = er[0].x ? (er[1].x ? (er[2].x ? (er[3].x ? 4 : 3) : 2) : 1) : 0;

    // ---- chunk-0 vector loads, unconditional (clamped), back-to-back ----
    float2 vvv[4];
    if (dg0) {
#pragma unroll
        for (int c = 0; c < 4; ++c) {
            int2 rc = (c < dg0) ? er[c] : er[0];
            *(float2*)&sk[wid][c][pf2] =
                *(const float2*)(keys + (size_t)rc.y * DVTOT + f2);
            vvv[c] = *(const float2*)(vals + (size_t)(rc.x - 1) * DVTOT + f2);
        }
    }
#pragma unroll
    for (int c = 0; c < 4; ++c) {
        int tc = (c < nq0) ? qt[c] : qt[0];
        *(float2*)&sq[wid][c][pf2] =
            *(const float2*)(qv + (size_t)((tc & 0x7FFFFFFF) - 1) * DVTOT + f2);
    }
    __builtin_amdgcn_wave_barrier();

    float kva[16], kvb[16], ks[16];
#pragma unroll
    for (int i = 0; i < 16; ++i) { kva[i] = 0.0f; kvb[i] = 0.0f; ks[i] = 0.0f; }

    // ---- chunk-0 k accumulate ----
#pragma unroll
    for (int c = 0; c < 4; ++c)
        if (c < dg0) KACC(c, vvv[c]);

    // ---- k chunk-1: records already in SGPRs (deg 5..8) ----
    if (dg0 == 4) {
        int n1 = er[4].x ? (er[5].x ? (er[6].x ? (er[7].x ? 4 : 3) : 2) : 1) : 0;
        if (n1) {
            float2 vv[4];
#pragma unroll
            for (int c = 0; c < 4; ++c) {
                int2 rc = (c < n1) ? er[4 + c] : er[4];
                vv[c] = *(const float2*)(vals + (size_t)(rc.x - 1) * DVTOT + f2);
            }
            __builtin_amdgcn_wave_barrier();         // WAR on sk
#pragma unroll
            for (int c = 0; c < 4; ++c) {
                int2 rc = (c < n1) ? er[4 + c] : er[4];
                *(float2*)&sk[wid][c][pf2] =
                    *(const float2*)(keys + (size_t)rc.y * DVTOT + f2);
            }
            __builtin_amdgcn_wave_barrier();
#pragma unroll
            for (int c = 0; c < 4; ++c)
                if (c < n1) KACC(c, vv[c]);
            // ---- deep k remainder (deg > 8): probe ----
            if (n1 == 4) {
                for (int base = 8; base < CAP; base += 4) {
                    int2 r[4];
#pragma unroll
                    for (int c = 0; c < 4; ++c) r[c] = eb[base + c];
                    int n = r[0].x ? (r[1].x ? (r[2].x ? (r[3].x ? 4 : 3) : 2) : 1) : 0;
                    if (n == 0) break;
                    float2 vr[4];
#pragma unroll
                    for (int c = 0; c < 4; ++c) {
                        int2 rc = (c < n) ? r[c] : r[0];
                        vr[c] = *(const float2*)(vals + (size_t)(rc.x - 1) * DVTOT + f2);
                    }
                    __builtin_amdgcn_wave_barrier();
#pragma unroll
                    for (int c = 0; c < 4; ++c) {
                        int2 rc = (c < n) ? r[c] : r[0];
                        *(float2*)&sk[wid][c][pf2] =
                            *(const float2*)(keys + (size_t)rc.y * DVTOT + f2);
                    }
                    __builtin_amdgcn_wave_barrier();
#pragma unroll
                    for (int c = 0; c < 4; ++c)
                        if (c < n) KACC(c, vr[c]);
                    if (n < 4) break;
                }
            }
        }
    }

    // ---- q outputs, chunk 0 (rows already staged) ----
#pragma unroll
    for (int c = 0; c < 4; ++c)
        if (c < nq0) QOUT(c, qt[c]);

    // ---- q chunk-1: records already in SGPRs (nq 5..8) ----
    if (nq0 == 4) {
        int n1 = qt[4] ? (qt[5] ? (qt[6] ? (qt[7] ? 4 : 3) : 2) : 1) : 0;
        if (n1) {
            float2 q2[4];
#pragma unroll
            for (int c = 0; c < 4; ++c) {
                int tc = (c < n1) ? qt[4 + c] : qt[4];
                q2[c] = *(const float2*)(qv + (size_t)((tc & 0x7FFFFFFF) - 1) * DVTOT + f2);
            }
            __builtin_amdgcn_wave_barrier();         // WAR on sq
#pragma unroll
            for (int c = 0; c < 4; ++c)
                *(float2*)&sq[wid][c][pf2] = q2[c];
            __builtin_amdgcn_wave_barrier();
#pragma unroll
            for (int c = 0; c < 4; ++c)
                if (c < n1) QOUT(c, qt[4 + c]);
            // ---- deep q remainder (nq > 8): probe ----
            if (n1 == 4) {
                for (int base = 8; base < CAP; base += 4) {
                    int t[4];
#pragma unroll
                    for (int c = 0; c < 4; ++c) t[c] = qb[base + c];
                    int n = t[0] ? (t[1] ? (t[2] ? (t[3] ? 4 : 3) : 2) : 1) : 0;
                    if (n == 0) break;
                    float2 qr[4];
#pragma unroll
                    for (int c = 0; c < 4; ++c) {
                        int tc = (c < n) ? t[c] : t[0];
                        qr[c] = *(const float2*)(qv + (size_t)((tc & 0x7FFFFFFF) - 1) * DVTOT + f2);
                    }
                    __builtin_amdgcn_wave_barrier();
#pragma unroll
                    for (int c = 0; c < 4; ++c)
                        *(float2*)&sq[wid][c][pf2] = qr[c];
                    __builtin_amdgcn_wave_barrier();
#pragma unroll
                    for (int c = 0; c < 4; ++c)
                        if (c < n) QOUT(c, t[c]);
                    if (n < 4) break;
                }
            }
        }
    }
}

extern "C" void kernel_launch(void* const* d_in, const int* in_sizes, int n_in,
                              void* d_out, int out_size, void* d_ws, size_t ws_size,
                              hipStream_t stream) {
    const float* qv   = (const float*)d_in[0];
    const float* keys = (const float*)d_in[1];
    const float* vals = (const float*)d_in[2];
    const int*   qidx = (const int*)d_in[3];
    const int*   vidx = (const int*)d_in[4];
    float* out = (float*)d_out;

    char* ws = (char*)d_ws;
    int*  ecnt = (int*)ws;                                // NTOT
    int*  qcnt = ecnt + NTOT;                             // NTOT
    int2* ebuf = (int2*)(qcnt + NTOT);                    // NTOT*CAP int2
    int*  qbuf = (int*)(ebuf + (size_t)NTOT * CAP);       // NTOT*CAP int

    zero_ws<<<ZERO_INT4 / 256, 256, 0, stream>>>((int4*)ws);
    fill_split<<<(2 * NV) / 256, 256, 0, stream>>>(qidx, vidx, ecnt, qcnt, ebuf, qbuf);
    attn_node<<<NTOT / 4, 256, 0, stream>>>(qv, keys, vals, ebuf, qbuf, out);
}